// Round 12
// baseline (645.118 us; speedup 1.0000x reference)
//
#include <hip/hip_runtime.h>
#include <hip/hip_bf16.h>

// ---- problem constants ----
#define N_NODES 32768
#define NGRAPH  64
#define NPG     512
#define TOPK    256
#define HID     256
#define FDIM    768
#define NEDGE   262144
#define NCLS    10
#define BN_EPS  1e-5f

#define IN_BF16 0
#define OUT_BF16 0

typedef __attribute__((ext_vector_type(8))) short short8;
typedef __attribute__((ext_vector_type(4))) float f32x4;

__device__ __forceinline__ float bf2f(unsigned short u) {
    return __uint_as_float(((unsigned)u) << 16);
}
__device__ __forceinline__ unsigned short f2bf(float f) {
    unsigned x = __float_as_uint(f);
    unsigned r = (x + 0x7fffu + ((x >> 16) & 1u)) >> 16;
    return (unsigned short)r;
}
__device__ __forceinline__ float in_ld(const void* p, size_t i) {
#if IN_BF16
    return bf2f(((const unsigned short*)p)[i]);
#else
    return ((const float*)p)[i];
#endif
}
__device__ __forceinline__ void st_out(void* o, size_t i, float v) {
#if OUT_BF16
    ((unsigned short*)o)[i] = f2bf(v);
#else
    ((float*)o)[i] = v;
#endif
}

__device__ __forceinline__ void async_cp16(const unsigned short* g, unsigned short* l) {
    __builtin_amdgcn_global_load_lds(
        (const __attribute__((address_space(1))) unsigned int*)g,
        (__attribute__((address_space(3))) unsigned int*)l, 16, 0, 0);
}

// XCD-aware tile swizzle (bijective; perf heuristic only)
__device__ __forceinline__ void tile_swizzle(int& bm, int& bn) {
    int nx = gridDim.x;
    int L = blockIdx.y * nx + blockIdx.x;
    int xcd = L & 7;
    int j = L >> 3;
    bm = ((j / nx) * 8 + xcd) * 128;
    bn = (j % nx) * 128;
}

// ---------------- conversions, one dispatch ----------------
__global__ __launch_bounds__(256) void cvt_all_kernel(const float* __restrict__ x,
                                                      const float* __restrict__ w_s1,
                                                      const float* __restrict__ w_s21,
                                                      const float* __restrict__ w_s22,
                                                      const float* __restrict__ w_raw,
                                                      const float* __restrict__ w_pool,
                                                      unsigned short* __restrict__ xbf,
                                                      unsigned short* __restrict__ wcat2,
                                                      unsigned short* __restrict__ wb_s22,
                                                      unsigned short* __restrict__ wb_raw,
                                                      unsigned short* __restrict__ wb_pool) {
    int id = blockIdx.x;
    if (id < 4096) {
        size_t base = (size_t)id * 2048 + threadIdx.x * 8;
        float4 a = *(const float4*)(x + base);
        float4 b = *(const float4*)(x + base + 4);
        unsigned short o[8] = { f2bf(a.x), f2bf(a.y), f2bf(a.z), f2bf(a.w),
                                f2bf(b.x), f2bf(b.y), f2bf(b.z), f2bf(b.w) };
        *(uint4*)(xbf + base) = *(uint4*)o;
        return;
    }
    __shared__ unsigned short tile[32][33];
    const float* src;
    unsigned short* dst;
    int K, N, t;
    if (id < 4160)      { src = w_s1;  dst = wcat2;                     K = 256; N = 256; t = id - 4096; }
    else if (id < 4224) { src = w_s21; dst = wcat2 + (size_t)256 * 256; K = 256; N = 256; t = id - 4160; }
    else if (id < 4288) { src = w_s22; dst = wb_s22;                    K = 256; N = 256; t = id - 4224; }
    else if (id < 4352) { src = w_raw; dst = wb_raw;                    K = 256; N = 256; t = id - 4288; }
    else                { src = w_pool; dst = wb_pool;                  K = 768; N = 768; t = id - 4352; }
    int tiles_x = K >> 5;
    int bk = (t % tiles_x) * 32, bn = (t / tiles_x) * 32;
    int tx = threadIdx.x & 31, ty = threadIdx.x >> 5;
#pragma unroll
    for (int i = 0; i < 32; i += 8)
        tile[ty + i][tx] = f2bf(src[(size_t)(bk + ty + i) * N + bn + tx]);
    __syncthreads();
#pragma unroll
    for (int i = 0; i < 32; i += 8)
        dst[(size_t)(bn + ty + i) * K + bk + tx] = tile[tx][ty + i];
}

// ---------------- edge dtype detection + CSR build ----------------
__global__ __launch_bounds__(256) void detect_kernel(const int* __restrict__ eb, int* __restrict__ flag) {
    int i = blockIdx.x * 256 + threadIdx.x;
    int v = eb[2 * (size_t)i + 1];
    unsigned long long b = __ballot(v != 0);
    if ((threadIdx.x & 63) == 0 && b)
        atomicAdd(flag, (int)__popcll(b));
}

__global__ __launch_bounds__(256) void hist_kernel(const int* __restrict__ eb, const int* __restrict__ flag,
                                                   int* __restrict__ deg) {
    int e = blockIdx.x * 256 + threadIdx.x;
    int st = (*flag == 0) ? 2 : 1;
    unsigned d = ((const unsigned*)eb)[(size_t)(NEDGE + e) * st] & (N_NODES - 1);
    atomicAdd(&deg[d], 1);
}

__global__ __launch_bounds__(1024) void scan_kernel(const int* __restrict__ cnt, int* __restrict__ rowptr,
                                                    int* __restrict__ cursor, float* __restrict__ dinv) {
    __shared__ int part[1024];
    int t = threadIdx.x;
    int base = t * 32;
    int loc[32];
    int s = 0;
#pragma unroll
    for (int i = 0; i < 32; i++) { loc[i] = cnt[base + i]; s += loc[i]; }
    part[t] = s;
    __syncthreads();
    for (int off = 1; off < 1024; off <<= 1) {
        int v = (t >= off) ? part[t - off] : 0;
        __syncthreads();
        part[t] += v;
        __syncthreads();
    }
    int run = (t == 0) ? 0 : part[t - 1];
#pragma unroll
    for (int i = 0; i < 32; i++) {
        rowptr[base + i] = run;
        cursor[base + i] = run;
        dinv[base + i] = rsqrtf((float)loc[i] + 1.0f);
        run += loc[i];
    }
    if (t == 1023) rowptr[N_NODES] = run;
}

__global__ __launch_bounds__(256) void scatter_kernel(const int* __restrict__ eb, const int* __restrict__ flag,
                                                      int* __restrict__ cursor, int* __restrict__ srcs) {
    int e = blockIdx.x * 256 + threadIdx.x;
    int st = (*flag == 0) ? 2 : 1;
    unsigned s = ((const unsigned*)eb)[(size_t)e * st] & (N_NODES - 1);
    unsigned d = ((const unsigned*)eb)[(size_t)(NEDGE + e) * st] & (N_NODES - 1);
    int p = atomicAdd(&cursor[d], 1);
    srcs[p] = (int)s;
}

// ---------------- GEMM body (128x128 tile, BK=64); caller sets A, WT, bm, bn ----------------
#define GEMM_BODY(K_)                                                           \
    __shared__ unsigned short As[128 * 64];                                     \
    __shared__ unsigned short Bs[128 * 64];                                     \
    const int tid = threadIdx.x;                                                \
    const int wave = tid >> 6;                                                  \
    const int lane = tid & 63;                                                  \
    const int wm = (wave >> 1) * 64;                                            \
    const int wn = (wave & 1) * 64;                                             \
    const int l15 = lane & 15;                                                  \
    const int q = lane >> 4;                                                    \
    f32x4 acc[4][4] = {};                                                       \
    const int srow = lane >> 3;                                                 \
    const int schunk = lane & 7;                                                \
    const int gc = schunk ^ srow;                                               \
    const unsigned short* gaA = A + (size_t)(bm + wave * 8 + srow) * (K_) + gc * 8;  \
    const unsigned short* gbB = WT + (size_t)(bn + wave * 8 + srow) * (K_) + gc * 8; \
    const size_t K32 = (size_t)(K_) * 32;                                       \
    unsigned short* const la0 = &As[(wave * 8) * 64];                           \
    unsigned short* const lb0 = &Bs[(wave * 8) * 64];                           \
    for (int k0 = 0; k0 < (K_); k0 += 64) {                                     \
        __syncthreads();                                                        \
        _Pragma("unroll")                                                       \
        for (int t = 0; t < 4; t++) {                                           \
            async_cp16(gaA + t * K32 + k0, la0 + t * 32 * 64);                  \
            async_cp16(gbB + t * K32 + k0, lb0 + t * 32 * 64);                  \
        }                                                                       \
        __syncthreads();                                                        \
        _Pragma("unroll")                                                       \
        for (int h = 0; h < 2; h++) {                                           \
            short8 af[4], bfv[4];                                               \
            int p = (h * 4 + q) ^ (l15 & 7);                                    \
            _Pragma("unroll")                                                   \
            for (int t = 0; t < 4; t++) {                                       \
                int m = wm + t * 16 + l15;                                      \
                int n = wn + t * 16 + l15;                                      \
                af[t] = *(const short8*)&As[m * 64 + p * 8];                    \
                bfv[t] = *(const short8*)&Bs[n * 64 + p * 8];                   \
            }                                                                   \
            _Pragma("unroll")                                                   \
            for (int tm = 0; tm < 4; tm++)                                      \
                _Pragma("unroll")                                               \
                for (int tn = 0; tn < 4; tn++)                                  \
                    acc[tm][tn] = __builtin_amdgcn_mfma_f32_16x16x32_bf16(af[tm], bfv[tn], acc[tm][tn], 0, 0, 0); \
        }                                                                       \
    }

// generic GEMM, runtime K. epi: 0 none, 1 sigmoid, 2 leaky-relu
__global__ __launch_bounds__(256) void gemm_kernel(const unsigned short* __restrict__ A,
                                                   const unsigned short* __restrict__ WT,
                                                   const float* __restrict__ bias,
                                                   unsigned short* __restrict__ C,
                                                   int K, int ldC, int colOff, int epi) {
    int bm, bn;
    tile_swizzle(bm, bn);
    GEMM_BODY(K)
#pragma unroll
    for (int tm = 0; tm < 4; tm++) {
        int row = bm + wm + tm * 16 + q * 4;
#pragma unroll
        for (int tn = 0; tn < 4; tn++) {
            int col = bn + wn + tn * 16 + l15;
            float bv = bias ? bias[col] : 0.0f;
#pragma unroll
            for (int r = 0; r < 4; r++) {
                float v = acc[tm][tn][r] + bv;
                if (epi == 1) v = 1.0f / (1.0f + __expf(-v));
                else if (epi == 2) v = v > 0.f ? v : 0.01f * v;
                C[(size_t)(row + r) * ldC + colOff + col] = f2bf(v);
            }
        }
    }
}

// heterogeneous merged dispatch (r10 proven), grid (6,256):
// swizzled tile-col 0-3: Xa @ wcat2 -> lrelu -> hfin[:,0:256] / t1
// swizzled tile-col 4-5: xbf @ wb_raw + b_raw -> hfin[:,512:768]
__global__ __launch_bounds__(256) void gemmA6_kernel(const unsigned short* __restrict__ Xa,
                                                     const unsigned short* __restrict__ wcat2,
                                                     const unsigned short* __restrict__ xbf,
                                                     const unsigned short* __restrict__ wb_raw,
                                                     const float* __restrict__ b_s1,
                                                     const float* __restrict__ b_s21,
                                                     const float* __restrict__ b_raw,
                                                     unsigned short* __restrict__ hfin,
                                                     unsigned short* __restrict__ t1) {
    const int nx = 6;
    int L = blockIdx.y * nx + blockIdx.x;
    int xcd = L & 7, j = L >> 3;
    int bm = ((j / nx) * 8 + xcd) * 128;
    int bnt = j % nx;
    int sub = (bnt < 4) ? 0 : 1;
    const unsigned short* A = sub ? xbf : Xa;
    const unsigned short* WT = sub ? wb_raw : wcat2;
    int bn = sub ? (bnt - 4) * 128 : bnt * 128;
    GEMM_BODY(256)
#pragma unroll
    for (int tm = 0; tm < 4; tm++) {
        int row = bm + wm + tm * 16 + q * 4;
#pragma unroll
        for (int tn = 0; tn < 4; tn++) {
            int col = bn + wn + tn * 16 + l15;
            if (sub == 0) {
                if (col < 256) {
                    float bv = b_s1[col];
#pragma unroll
                    for (int r = 0; r < 4; r++) {
                        float v = acc[tm][tn][r] + bv;
                        v = v > 0.f ? v : 0.01f * v;
                        hfin[(size_t)(row + r) * 768 + col] = f2bf(v);
                    }
                } else {
                    float bv = b_s21[col - 256];
#pragma unroll
                    for (int r = 0; r < 4; r++) {
                        float v = acc[tm][tn][r] + bv;
                        v = v > 0.f ? v : 0.01f * v;
                        t1[(size_t)(row + r) * 256 + (col - 256)] = f2bf(v);
                    }
                }
            } else {
                float bv = b_raw[col];
#pragma unroll
                for (int r = 0; r < 4; r++)
                    hfin[(size_t)(row + r) * 768 + 512 + col] = f2bf(acc[tm][tn][r] + bv);
            }
        }
    }
}

// ---------------- pure linear GCN aggregation (256-dim) ----------------
__global__ __launch_bounds__(256) void lin_agg_kernel(const unsigned short* __restrict__ h,
                                                      const int* __restrict__ rowptr, const int* __restrict__ srcs,
                                                      const float* __restrict__ dinv,
                                                      unsigned short* __restrict__ out) {
    int wave = threadIdx.x >> 6, lane = threadIdx.x & 63;
    int v = blockIdx.x * 4 + wave;
    int f0 = lane * 4;
    float a0 = 0.f, a1 = 0.f, a2 = 0.f, a3 = 0.f;
    int s = rowptr[v], e = rowptr[v + 1];
    for (int i = s; i < e; i++) {
        int u = srcs[i] & (N_NODES - 1);
        float du = dinv[u];
        uint2 hv = *(const uint2*)(h + (size_t)u * 256 + f0);
        a0 += bf2f((unsigned short)(hv.x & 0xffff)) * du;
        a1 += bf2f((unsigned short)(hv.x >> 16)) * du;
        a2 += bf2f((unsigned short)(hv.y & 0xffff)) * du;
        a3 += bf2f((unsigned short)(hv.y >> 16)) * du;
    }
    float dv = dinv[v], dv2 = dv * dv;
    uint2 sv = *(const uint2*)(h + (size_t)v * 256 + f0);
    float r0 = dv * a0 + bf2f((unsigned short)(sv.x & 0xffff)) * dv2;
    float r1 = dv * a1 + bf2f((unsigned short)(sv.x >> 16)) * dv2;
    float r2 = dv * a2 + bf2f((unsigned short)(sv.y & 0xffff)) * dv2;
    float r3 = dv * a3 + bf2f((unsigned short)(sv.y >> 16)) * dv2;
    uint2 ov = make_uint2(((unsigned)f2bf(r1) << 16) | f2bf(r0), ((unsigned)f2bf(r3) << 16) | f2bf(r2));
    *(uint2*)(out + (size_t)v * 256 + f0) = ov;
}

// ---------------- score matvec ----------------
__global__ __launch_bounds__(256) void score_mv_kernel(const unsigned short* __restrict__ hf,
                                                       const void* __restrict__ wp, const void* __restrict__ wn,
                                                       float* __restrict__ svp, float* __restrict__ svn) {
    int wave = threadIdx.x >> 6, lane = threadIdx.x & 63;
    int v = blockIdx.x * 4 + wave;
    float sp = 0.f, sn = 0.f;
#pragma unroll
    for (int i = 0; i < 3; i++) {
        int k = i * 256 + lane * 4;
        uint2 hv = *(const uint2*)(hf + (size_t)v * 768 + k);
        float x0 = bf2f((unsigned short)(hv.x & 0xffff));
        float x1 = bf2f((unsigned short)(hv.x >> 16));
        float x2 = bf2f((unsigned short)(hv.y & 0xffff));
        float x3 = bf2f((unsigned short)(hv.y >> 16));
        sp += x0 * in_ld(wp, k) + x1 * in_ld(wp, k + 1) + x2 * in_ld(wp, k + 2) + x3 * in_ld(wp, k + 3);
        sn += x0 * in_ld(wn, k) + x1 * in_ld(wn, k + 1) + x2 * in_ld(wn, k + 2) + x3 * in_ld(wn, k + 3);
    }
    for (int off = 32; off >= 1; off >>= 1) {
        sp += __shfl_down(sp, off, 64);
        sn += __shfl_down(sn, off, 64);
    }
    if (lane == 0) { svp[v] = sp; svn[v] = sn; }
}

// ---------------- fused: score aggregation + sigmoid + outputs + dual top-k ----------------
__global__ __launch_bounds__(512) void score_topk_kernel(const float* __restrict__ svp, const float* __restrict__ svn,
                                                         const int* __restrict__ rowptr, const int* __restrict__ srcs,
                                                         const float* __restrict__ dinv,
                                                         const void* __restrict__ bp, const void* __restrict__ bn_,
                                                         unsigned char* __restrict__ maskp,
                                                         unsigned char* __restrict__ maskn,
                                                         void* __restrict__ dout) {
    __shared__ float sp[512], sn[512];
    int g = blockIdx.x, i = threadIdx.x;
    int v = g * 512 + i;
    float ap = 0.f, an = 0.f;
    int s = rowptr[v], e = rowptr[v + 1];
    for (int k = s; k < e; k++) {
        int u = srcs[k] & (N_NODES - 1);
        float du = dinv[u];
        ap += svp[u] * du;
        an += svn[u] * du;
    }
    float dv = dinv[v], dv2 = dv * dv;
    float zp = dv * ap + svp[v] * dv2 + in_ld(bp, 0);
    float zn = dv * an + svn[v] * dv2 + in_ld(bn_, 0);
    float pp = 1.0f / (1.0f + __expf(-zp));
    float pn = 1.0f / (1.0f + __expf(-zn));
    st_out(dout, 1920 + (size_t)v, pp);
    st_out(dout, 1920 + (size_t)N_NODES + v, pn);
    st_out(dout, 1920 + 2 * (size_t)N_NODES + v, (float)g);
    sp[i] = pp; sn[i] = pn;
    __syncthreads();
    int cp = 0, cn = 0;
    for (int j = 0; j < 512; j++) {
        float op = sp[j], on = sn[j];
        cp += (int)((op > pp) || ((op == pp) && (j < i)));
        cn += (int)((on > pn) || ((on == pn) && (j < i)));
    }
    maskp[v] = (cp < TOPK) ? 1 : 0;
    maskn[v] = (cn < TOPK) ? 1 : 0;
}

// ---------------- fused dual-mask readout ----------------
__global__ __launch_bounds__(256) void readout2_kernel(const unsigned short* __restrict__ xt,
                                                       const unsigned char* __restrict__ maskp,
                                                       const unsigned char* __restrict__ maskn,
                                                       float* __restrict__ eout) {
    int g = blockIdx.x;
    int c = blockIdx.y;
    int wv = threadIdx.x >> 6, lane = threadIdx.x & 63;
    int f = c * 64 + lane;
    __shared__ unsigned char mp[512], mn[512];
    __shared__ float red[4][64][4];
    for (int i = threadIdx.x; i < 512; i += 256) {
        mp[i] = maskp[(size_t)g * 512 + i];
        mn[i] = maskn[(size_t)g * 512 + i];
    }
    __syncthreads();
    float sp = 0.f, sn = 0.f, xp = -INFINITY, xn = -INFINITY;
    const unsigned short* base = xt + ((size_t)g * 512 + wv * 128) * 768 + f;
    for (int v = 0; v < 128; v++) {
        unsigned char bp = mp[wv * 128 + v], bn_ = mn[wv * 128 + v];
        if (!(bp | bn_)) continue;
        float x = bf2f(base[(size_t)v * 768]);
        if (bp) { sp += x; xp = fmaxf(xp, x); }
        if (bn_) { sn += x; xn = fmaxf(xn, x); }
    }
    red[wv][lane][0] = sp; red[wv][lane][1] = xp;
    red[wv][lane][2] = sn; red[wv][lane][3] = xn;
    __syncthreads();
    if (wv == 0) {
#pragma unroll
        for (int w = 1; w < 4; w++) {
            sp += red[w][lane][0]; xp = fmaxf(xp, red[w][lane][1]);
            sn += red[w][lane][2]; xn = fmaxf(xn, red[w][lane][3]);
        }
        float* erp = eout + (size_t)g * 1536;
        float* ern = eout + (size_t)(64 + g) * 1536;
        erp[f] = sp * (1.0f / TOPK);
        erp[768 + f] = xp;
        ern[f] = sn * (1.0f / TOPK);
        ern[768 + f] = xn;
    }
}

// ---------------- fused MLP layer: GEMM + bias + BN(group of 64 rows) + relu + residual ----------------
// grid (2 groups, 16 colgroups), 256 threads. Thread t: col = cg*16 + (t&15),
// rows = g*64 + (t>>4)*4 .. +3. Block owns ALL 64 rows of its group for its
// 16 cols -> BN stats are fully in-block.
__global__ __launch_bounds__(256) void mlp_layer_kernel(const float* __restrict__ in,
                                                        const float* __restrict__ W,
                                                        const float* __restrict__ b,
                                                        const float* __restrict__ gamma,
                                                        const float* __restrict__ beta,
                                                        const float* __restrict__ res,
                                                        float* __restrict__ out, int K) {
    __shared__ float inS[64][129];
    __shared__ float wS[128][17];
    __shared__ float red[16][16][2];
    __shared__ float mv[16][2];
    int g = blockIdx.x, cg = blockIdx.y;
    int t = threadIdx.x;
    int c16 = t & 15, rb = t >> 4;
    int col = cg * 16 + c16;
    float acc[4] = {0.f, 0.f, 0.f, 0.f};
    for (int k0 = 0; k0 < K; k0 += 128) {
        __syncthreads();
        for (int idx = t; idx < 64 * 128; idx += 256) {
            int r = idx >> 7, kk = idx & 127;
            inS[r][kk] = in[(size_t)(g * 64 + r) * K + k0 + kk];
        }
        for (int idx = t; idx < 128 * 16; idx += 256) {
            int k = idx >> 4, c = idx & 15;
            wS[k][c] = W[(size_t)(k0 + k) * 256 + cg * 16 + c];
        }
        __syncthreads();
        for (int k = 0; k < 128; k++) {
            float w = wS[k][c16];
            acc[0] += inS[rb * 4 + 0][k] * w;
            acc[1] += inS[rb * 4 + 1][k] * w;
            acc[2] += inS[rb * 4 + 2][k] * w;
            acc[3] += inS[rb * 4 + 3][k] * w;
        }
    }
    float bv = b[col];
#pragma unroll
    for (int j = 0; j < 4; j++) acc[j] += bv;
    float s = acc[0] + acc[1] + acc[2] + acc[3];
    float sq = acc[0] * acc[0] + acc[1] * acc[1] + acc[2] * acc[2] + acc[3] * acc[3];
    red[rb][c16][0] = s;
    red[rb][c16][1] = sq;
    __syncthreads();
    if (rb == 0) {
        float S = 0.f, Q = 0.f;
#pragma unroll
        for (int i = 0; i < 16; i++) { S += red[i][c16][0]; Q += red[i][c16][1]; }
        float m = S * (1.0f / 64.0f);
        mv[c16][0] = m;
        mv[c16][1] = rsqrtf(Q * (1.0f / 64.0f) - m * m + BN_EPS);
    }
    __syncthreads();
    float m = mv[c16][0], inv = mv[c16][1];
    float ga = gamma[col], be = beta[col];
#pragma unroll
    for (int j = 0; j < 4; j++) {
        int row = g * 64 + rb * 4 + j;
        float y = (acc[j] - m) * inv * ga + be;
        y = fmaxf(y, 0.0f);
        if (res) y += res[(size_t)row * 256 + col];
        out[(size_t)row * 256 + col] = y;
    }
}

// fused logits + softmax
__global__ __launch_bounds__(64) void head_kernel(const float* __restrict__ act, const void* __restrict__ w4,
                                                  const void* __restrict__ b4, void* __restrict__ dout) {
    __shared__ float l[NCLS];
    int r = blockIdx.x, t = threadIdx.x;
    if (t < NCLS) {
        float acc = in_ld(b4, t);
        for (int k = 0; k < 256; k++)
            acc += act[(size_t)r * 256 + k] * in_ld(w4, (size_t)k * NCLS + t);
        l[t] = acc;
    }
    __syncthreads();
    if (t == 0) {
        float mx = -1e30f;
        for (int c = 0; c < NCLS; c++) mx = fmaxf(mx, l[c]);
        float ex[NCLS], sum = 0.f;
        for (int c = 0; c < NCLS; c++) { ex[c] = __expf(l[c] - mx); sum += ex[c]; }
        float inv = 1.0f / sum;
        int g = r >> 6, rr = r & 63;
        if (g == 0) {
            for (int c = 0; c < NCLS; c++) st_out(dout, (size_t)rr * NCLS + c, l[c]);
            for (int c = 0; c < NCLS; c++) st_out(dout, 640 + (size_t)rr * NCLS + c, ex[c] * inv);
        } else {
            for (int c = 0; c < NCLS; c++) st_out(dout, 1280 + (size_t)rr * NCLS + c, ex[c] * inv);
        }
    }
}

// ---------------- host launcher ----------------
extern "C" void kernel_launch(void* const* d_in, const int* in_sizes, int n_in,
                              void* d_out, int out_size, void* d_ws, size_t ws_size,
                              hipStream_t stream) {
    (void)in_sizes; (void)n_in; (void)out_size; (void)ws_size;

    const float* x = (const float*)d_in[0];
    const int* eb = (const int*)d_in[1];
    const float* w_s1 = (const float*)d_in[3];
    const float* b_s1 = (const float*)d_in[4];
    const float* w_s21 = (const float*)d_in[5];
    const float* b_s21 = (const float*)d_in[6];
    const float* w_s22 = (const float*)d_in[7];
    const float* b_s22 = (const float*)d_in[8];
    const float* w_raw = (const float*)d_in[9];
    const float* b_raw = (const float*)d_in[10];
    const void* w_pos = d_in[11];
    const void* b_pos = d_in[12];
    const void* w_neg = d_in[13];
    const void* b_neg = d_in[14];
    const float* w_pool = (const float*)d_in[15];
    const float* b_pool = (const float*)d_in[16];
    const float* w1 = (const float*)d_in[17];  const float* b1 = (const float*)d_in[18];
    const float* g1 = (const float*)d_in[19];  const float* be1 = (const float*)d_in[20];
    const float* w2 = (const float*)d_in[21];  const float* b2 = (const float*)d_in[22];
    const float* g2 = (const float*)d_in[23];  const float* be2 = (const float*)d_in[24];
    const float* w3 = (const float*)d_in[25];  const float* b3 = (const float*)d_in[26];
    const float* g3 = (const float*)d_in[27];  const float* be3 = (const float*)d_in[28];
    const void* w4 = d_in[29];  const void* b4 = d_in[30];

    char* ws = (char*)d_ws;
    size_t off = 0;
    auto alloc = [&](size_t b) -> void* {
        void* p = ws + off;
        off += (b + 255) & ~(size_t)255;
        return p;
    };
    int* flag = (int*)alloc(256);
    int* deg = (int*)alloc((size_t)N_NODES * 4);           // contiguous after flag
    float* dinv = (float*)alloc((size_t)N_NODES * 4);
    int* rowptr = (int*)alloc((size_t)(N_NODES + 1) * 4);
    int* cursor = (int*)alloc((size_t)N_NODES * 4);
    int* srcs = (int*)alloc((size_t)NEDGE * 4);
    unsigned short* xbf = (unsigned short*)alloc((size_t)N_NODES * 256 * 2);
    unsigned short* wcat2 = (unsigned short*)alloc((size_t)512 * 256 * 2);
    unsigned short* wb_s22 = (unsigned short*)alloc((size_t)256 * 256 * 2);
    unsigned short* wb_raw = (unsigned short*)alloc((size_t)256 * 256 * 2);
    unsigned short* wb_pool = (unsigned short*)alloc((size_t)768 * 768 * 2);
    unsigned short* Xa = (unsigned short*)alloc((size_t)N_NODES * 256 * 2);
    unsigned short* t1 = (unsigned short*)alloc((size_t)N_NODES * 256 * 2);
    unsigned short* t1a = (unsigned short*)alloc((size_t)N_NODES * 256 * 2);
    unsigned short* hfin = (unsigned short*)alloc((size_t)N_NODES * 768 * 2);
    unsigned short* xt = (unsigned short*)alloc((size_t)N_NODES * 768 * 2);
    float* svp = (float*)alloc((size_t)N_NODES * 4);
    float* svn = (float*)alloc((size_t)N_NODES * 4);
    unsigned char* maskp = (unsigned char*)alloc(N_NODES);
    unsigned char* maskn = (unsigned char*)alloc(N_NODES);
    float* ebuf = (float*)alloc((size_t)128 * 1536 * 4);
    float* act1 = (float*)alloc((size_t)128 * 256 * 4);
    float* act2 = (float*)alloc((size_t)128 * 256 * 4);
    float* act3 = (float*)alloc((size_t)128 * 256 * 4);

    hipMemsetAsync(flag, 0, 256 + (size_t)N_NODES * 4, stream);

    detect_kernel<<<NEDGE / 256, 256, 0, stream>>>(eb, flag);
    hist_kernel<<<NEDGE / 256, 256, 0, stream>>>(eb, flag, deg);
    scan_kernel<<<1, 1024, 0, stream>>>(deg, rowptr, cursor, dinv);
    scatter_kernel<<<NEDGE / 256, 256, 0, stream>>>(eb, flag, cursor, srcs);

    cvt_all_kernel<<<4928, 256, 0, stream>>>(x, w_s1, w_s21, w_s22, w_raw, w_pool,
                                             xbf, wcat2, wb_s22, wb_raw, wb_pool);

    dim3 gA6(6, N_NODES / 128);
    dim3 gA1(2, N_NODES / 128);
    dim3 gP(6, N_NODES / 128);

    // GCN pipeline (r10 proven configuration)
    lin_agg_kernel<<<N_NODES / 4, 256, 0, stream>>>(xbf, rowptr, srcs, dinv, Xa);
    gemmA6_kernel<<<gA6, 256, 0, stream>>>(Xa, wcat2, xbf, wb_raw, b_s1, b_s21, b_raw, hfin, t1);
    lin_agg_kernel<<<N_NODES / 4, 256, 0, stream>>>(t1, rowptr, srcs, dinv, t1a);
    gemm_kernel<<<gA1, 256, 0, stream>>>(t1a, wb_s22, b_s22, hfin, 256, 768, 256, 2);
    // pool (N=768 proven shape, plain epilogue)
    gemm_kernel<<<gP, 256, 0, stream>>>(hfin, wb_pool, b_pool, xt, 768, 768, 0, 1);
    // scores + top-k (fused) + readout
    score_mv_kernel<<<N_NODES / 4, 256, 0, stream>>>(hfin, w_pos, w_neg, svp, svn);
    score_topk_kernel<<<NGRAPH, 512, 0, stream>>>(svp, svn, rowptr, srcs, dinv, b_pos, b_neg,
                                                  maskp, maskn, d_out);
    {
        dim3 gR(NGRAPH, FDIM / 64);
        readout2_kernel<<<gR, 256, 0, stream>>>(xt, maskp, maskn, ebuf);
    }
    // fused MLP: 3 layer kernels (GEMM+BN+relu+residual in-block)
    {
        dim3 gL(2, 16);
        mlp_layer_kernel<<<gL, 256, 0, stream>>>(ebuf, w1, b1, g1, be1, nullptr, act1, 1536);
        mlp_layer_kernel<<<gL, 256, 0, stream>>>(act1, w2, b2, g2, be2, act1, act2, 256);
        mlp_layer_kernel<<<gL, 256, 0, stream>>>(act2, w3, b3, g3, be3, act2, act3, 256);
    }
    head_kernel<<<128, 64, 0, stream>>>(act3, w4, b4, d_out);
}

// Round 13
// 569.613 us; speedup vs baseline: 1.1326x; 1.1326x over previous
//
#include <hip/hip_runtime.h>
#include <hip/hip_bf16.h>

// ---- problem constants ----
#define N_NODES 32768
#define NGRAPH  64
#define NPG     512
#define TOPK    256
#define HID     256
#define FDIM    768
#define NEDGE   262144
#define NCLS    10
#define BN_EPS  1e-5f

#define IN_BF16 0
#define OUT_BF16 0

typedef __attribute__((ext_vector_type(8))) short short8;
typedef __attribute__((ext_vector_type(4))) float f32x4;

__device__ __forceinline__ float bf2f(unsigned short u) {
    return __uint_as_float(((unsigned)u) << 16);
}
__device__ __forceinline__ unsigned short f2bf(float f) {
    unsigned x = __float_as_uint(f);
    unsigned r = (x + 0x7fffu + ((x >> 16) & 1u)) >> 16;
    return (unsigned short)r;
}
__device__ __forceinline__ float in_ld(const void* p, size_t i) {
#if IN_BF16
    return bf2f(((const unsigned short*)p)[i]);
#else
    return ((const float*)p)[i];
#endif
}
__device__ __forceinline__ void st_out(void* o, size_t i, float v) {
#if OUT_BF16
    ((unsigned short*)o)[i] = f2bf(v);
#else
    ((float*)o)[i] = v;
#endif
}

__device__ __forceinline__ void async_cp16(const unsigned short* g, unsigned short* l) {
    __builtin_amdgcn_global_load_lds(
        (const __attribute__((address_space(1))) unsigned int*)g,
        (__attribute__((address_space(3))) unsigned int*)l, 16, 0, 0);
}

// XCD-aware tile swizzle (bijective; perf heuristic only)
__device__ __forceinline__ void tile_swizzle(int& bm, int& bn) {
    int nx = gridDim.x;
    int L = blockIdx.y * nx + blockIdx.x;
    int xcd = L & 7;
    int j = L >> 3;
    bm = ((j / nx) * 8 + xcd) * 128;
    bn = (j % nx) * 128;
}

// ---------------- conversions, one dispatch ----------------
__global__ __launch_bounds__(256) void cvt_all_kernel(const float* __restrict__ x,
                                                      const float* __restrict__ w_s1,
                                                      const float* __restrict__ w_s21,
                                                      const float* __restrict__ w_s22,
                                                      const float* __restrict__ w_raw,
                                                      const float* __restrict__ w_pool,
                                                      unsigned short* __restrict__ xbf,
                                                      unsigned short* __restrict__ wcat2,
                                                      unsigned short* __restrict__ wb_s22,
                                                      unsigned short* __restrict__ wb_raw,
                                                      unsigned short* __restrict__ wb_pool) {
    int id = blockIdx.x;
    if (id < 4096) {
        size_t base = (size_t)id * 2048 + threadIdx.x * 8;
        float4 a = *(const float4*)(x + base);
        float4 b = *(const float4*)(x + base + 4);
        unsigned short o[8] = { f2bf(a.x), f2bf(a.y), f2bf(a.z), f2bf(a.w),
                                f2bf(b.x), f2bf(b.y), f2bf(b.z), f2bf(b.w) };
        *(uint4*)(xbf + base) = *(uint4*)o;
        return;
    }
    __shared__ unsigned short tile[32][33];
    const float* src;
    unsigned short* dst;
    int K, N, t;
    if (id < 4160)      { src = w_s1;  dst = wcat2;                     K = 256; N = 256; t = id - 4096; }
    else if (id < 4224) { src = w_s21; dst = wcat2 + (size_t)256 * 256; K = 256; N = 256; t = id - 4160; }
    else if (id < 4288) { src = w_s22; dst = wb_s22;                    K = 256; N = 256; t = id - 4224; }
    else if (id < 4352) { src = w_raw; dst = wb_raw;                    K = 256; N = 256; t = id - 4288; }
    else                { src = w_pool; dst = wb_pool;                  K = 768; N = 768; t = id - 4352; }
    int tiles_x = K >> 5;
    int bk = (t % tiles_x) * 32, bn = (t / tiles_x) * 32;
    int tx = threadIdx.x & 31, ty = threadIdx.x >> 5;
#pragma unroll
    for (int i = 0; i < 32; i += 8)
        tile[ty + i][tx] = f2bf(src[(size_t)(bk + ty + i) * N + bn + tx]);
    __syncthreads();
#pragma unroll
    for (int i = 0; i < 32; i += 8)
        dst[(size_t)(bn + ty + i) * K + bk + tx] = tile[tx][ty + i];
}

// ---------------- edge dtype detection + CSR build ----------------
__global__ __launch_bounds__(256) void detect_kernel(const int* __restrict__ eb, int* __restrict__ flag) {
    int i = blockIdx.x * 256 + threadIdx.x;
    int v = eb[2 * (size_t)i + 1];
    unsigned long long b = __ballot(v != 0);
    if ((threadIdx.x & 63) == 0 && b)
        atomicAdd(flag, (int)__popcll(b));
}

__global__ __launch_bounds__(256) void hist_kernel(const int* __restrict__ eb, const int* __restrict__ flag,
                                                   int* __restrict__ deg) {
    int e = blockIdx.x * 256 + threadIdx.x;
    int st = (*flag == 0) ? 2 : 1;
    unsigned d = ((const unsigned*)eb)[(size_t)(NEDGE + e) * st] & (N_NODES - 1);
    atomicAdd(&deg[d], 1);
}

__global__ __launch_bounds__(1024) void scan_kernel(const int* __restrict__ cnt, int* __restrict__ rowptr,
                                                    int* __restrict__ cursor, float* __restrict__ dinv) {
    __shared__ int part[1024];
    int t = threadIdx.x;
    int base = t * 32;
    int loc[32];
    int s = 0;
#pragma unroll
    for (int i = 0; i < 32; i++) { loc[i] = cnt[base + i]; s += loc[i]; }
    part[t] = s;
    __syncthreads();
    for (int off = 1; off < 1024; off <<= 1) {
        int v = (t >= off) ? part[t - off] : 0;
        __syncthreads();
        part[t] += v;
        __syncthreads();
    }
    int run = (t == 0) ? 0 : part[t - 1];
#pragma unroll
    for (int i = 0; i < 32; i++) {
        rowptr[base + i] = run;
        cursor[base + i] = run;
        dinv[base + i] = rsqrtf((float)loc[i] + 1.0f);
        run += loc[i];
    }
    if (t == 1023) rowptr[N_NODES] = run;
}

__global__ __launch_bounds__(256) void scatter_kernel(const int* __restrict__ eb, const int* __restrict__ flag,
                                                      int* __restrict__ cursor, int* __restrict__ srcs) {
    int e = blockIdx.x * 256 + threadIdx.x;
    int st = (*flag == 0) ? 2 : 1;
    unsigned s = ((const unsigned*)eb)[(size_t)e * st] & (N_NODES - 1);
    unsigned d = ((const unsigned*)eb)[(size_t)(NEDGE + e) * st] & (N_NODES - 1);
    int p = atomicAdd(&cursor[d], 1);
    srcs[p] = (int)s;
}

// ---------------- GEMM body (128x128 tile, BK=64); caller sets A, WT, bm, bn ----------------
#define GEMM_BODY(K_)                                                           \
    __shared__ unsigned short As[128 * 64];                                     \
    __shared__ unsigned short Bs[128 * 64];                                     \
    const int tid = threadIdx.x;                                                \
    const int wave = tid >> 6;                                                  \
    const int lane = tid & 63;                                                  \
    const int wm = (wave >> 1) * 64;                                            \
    const int wn = (wave & 1) * 64;                                             \
    const int l15 = lane & 15;                                                  \
    const int q = lane >> 4;                                                    \
    f32x4 acc[4][4] = {};                                                       \
    const int srow = lane >> 3;                                                 \
    const int schunk = lane & 7;                                                \
    const int gc = schunk ^ srow;                                               \
    const unsigned short* gaA = A + (size_t)(bm + wave * 8 + srow) * (K_) + gc * 8;  \
    const unsigned short* gbB = WT + (size_t)(bn + wave * 8 + srow) * (K_) + gc * 8; \
    const size_t K32 = (size_t)(K_) * 32;                                       \
    unsigned short* const la0 = &As[(wave * 8) * 64];                           \
    unsigned short* const lb0 = &Bs[(wave * 8) * 64];                           \
    for (int k0 = 0; k0 < (K_); k0 += 64) {                                     \
        __syncthreads();                                                        \
        _Pragma("unroll")                                                       \
        for (int t = 0; t < 4; t++) {                                           \
            async_cp16(gaA + t * K32 + k0, la0 + t * 32 * 64);                  \
            async_cp16(gbB + t * K32 + k0, lb0 + t * 32 * 64);                  \
        }                                                                       \
        __syncthreads();                                                        \
        _Pragma("unroll")                                                       \
        for (int h = 0; h < 2; h++) {                                           \
            short8 af[4], bfv[4];                                               \
            int p = (h * 4 + q) ^ (l15 & 7);                                    \
            _Pragma("unroll")                                                   \
            for (int t = 0; t < 4; t++) {                                       \
                int m = wm + t * 16 + l15;                                      \
                int n = wn + t * 16 + l15;                                      \
                af[t] = *(const short8*)&As[m * 64 + p * 8];                    \
                bfv[t] = *(const short8*)&Bs[n * 64 + p * 8];                   \
            }                                                                   \
            _Pragma("unroll")                                                   \
            for (int tm = 0; tm < 4; tm++)                                      \
                _Pragma("unroll")                                               \
                for (int tn = 0; tn < 4; tn++)                                  \
                    acc[tm][tn] = __builtin_amdgcn_mfma_f32_16x16x32_bf16(af[tm], bfv[tn], acc[tm][tn], 0, 0, 0); \
        }                                                                       \
    }

// generic GEMM, runtime K. epi: 0 none, 1 sigmoid, 2 leaky-relu
__global__ __launch_bounds__(256) void gemm_kernel(const unsigned short* __restrict__ A,
                                                   const unsigned short* __restrict__ WT,
                                                   const float* __restrict__ bias,
                                                   unsigned short* __restrict__ C,
                                                   int K, int ldC, int colOff, int epi) {
    int bm, bn;
    tile_swizzle(bm, bn);
    GEMM_BODY(K)
#pragma unroll
    for (int tm = 0; tm < 4; tm++) {
        int row = bm + wm + tm * 16 + q * 4;
#pragma unroll
        for (int tn = 0; tn < 4; tn++) {
            int col = bn + wn + tn * 16 + l15;
            float bv = bias ? bias[col] : 0.0f;
#pragma unroll
            for (int r = 0; r < 4; r++) {
                float v = acc[tm][tn][r] + bv;
                if (epi == 1) v = 1.0f / (1.0f + __expf(-v));
                else if (epi == 2) v = v > 0.f ? v : 0.01f * v;
                C[(size_t)(row + r) * ldC + colOff + col] = f2bf(v);
            }
        }
    }
}

// heterogeneous merged dispatch (r10 proven), grid (6,256):
// swizzled tile-col 0-3: Xa @ wcat2 -> lrelu -> hfin[:,0:256] / t1
// swizzled tile-col 4-5: xbf @ wb_raw + b_raw -> hfin[:,512:768]
__global__ __launch_bounds__(256) void gemmA6_kernel(const unsigned short* __restrict__ Xa,
                                                     const unsigned short* __restrict__ wcat2,
                                                     const unsigned short* __restrict__ xbf,
                                                     const unsigned short* __restrict__ wb_raw,
                                                     const float* __restrict__ b_s1,
                                                     const float* __restrict__ b_s21,
                                                     const float* __restrict__ b_raw,
                                                     unsigned short* __restrict__ hfin,
                                                     unsigned short* __restrict__ t1) {
    const int nx = 6;
    int L = blockIdx.y * nx + blockIdx.x;
    int xcd = L & 7, j = L >> 3;
    int bm = ((j / nx) * 8 + xcd) * 128;
    int bnt = j % nx;
    int sub = (bnt < 4) ? 0 : 1;
    const unsigned short* A = sub ? xbf : Xa;
    const unsigned short* WT = sub ? wb_raw : wcat2;
    int bn = sub ? (bnt - 4) * 128 : bnt * 128;
    GEMM_BODY(256)
#pragma unroll
    for (int tm = 0; tm < 4; tm++) {
        int row = bm + wm + tm * 16 + q * 4;
#pragma unroll
        for (int tn = 0; tn < 4; tn++) {
            int col = bn + wn + tn * 16 + l15;
            if (sub == 0) {
                if (col < 256) {
                    float bv = b_s1[col];
#pragma unroll
                    for (int r = 0; r < 4; r++) {
                        float v = acc[tm][tn][r] + bv;
                        v = v > 0.f ? v : 0.01f * v;
                        hfin[(size_t)(row + r) * 768 + col] = f2bf(v);
                    }
                } else {
                    float bv = b_s21[col - 256];
#pragma unroll
                    for (int r = 0; r < 4; r++) {
                        float v = acc[tm][tn][r] + bv;
                        v = v > 0.f ? v : 0.01f * v;
                        t1[(size_t)(row + r) * 256 + (col - 256)] = f2bf(v);
                    }
                }
            } else {
                float bv = b_raw[col];
#pragma unroll
                for (int r = 0; r < 4; r++)
                    hfin[(size_t)(row + r) * 768 + 512 + col] = f2bf(acc[tm][tn][r] + bv);
            }
        }
    }
}

// ---------------- pure linear GCN aggregation (256-dim) ----------------
__global__ __launch_bounds__(256) void lin_agg_kernel(const unsigned short* __restrict__ h,
                                                      const int* __restrict__ rowptr, const int* __restrict__ srcs,
                                                      const float* __restrict__ dinv,
                                                      unsigned short* __restrict__ out) {
    int wave = threadIdx.x >> 6, lane = threadIdx.x & 63;
    int v = blockIdx.x * 4 + wave;
    int f0 = lane * 4;
    float a0 = 0.f, a1 = 0.f, a2 = 0.f, a3 = 0.f;
    int s = rowptr[v], e = rowptr[v + 1];
    for (int i = s; i < e; i++) {
        int u = srcs[i] & (N_NODES - 1);
        float du = dinv[u];
        uint2 hv = *(const uint2*)(h + (size_t)u * 256 + f0);
        a0 += bf2f((unsigned short)(hv.x & 0xffff)) * du;
        a1 += bf2f((unsigned short)(hv.x >> 16)) * du;
        a2 += bf2f((unsigned short)(hv.y & 0xffff)) * du;
        a3 += bf2f((unsigned short)(hv.y >> 16)) * du;
    }
    float dv = dinv[v], dv2 = dv * dv;
    uint2 sv = *(const uint2*)(h + (size_t)v * 256 + f0);
    float r0 = dv * a0 + bf2f((unsigned short)(sv.x & 0xffff)) * dv2;
    float r1 = dv * a1 + bf2f((unsigned short)(sv.x >> 16)) * dv2;
    float r2 = dv * a2 + bf2f((unsigned short)(sv.y & 0xffff)) * dv2;
    float r3 = dv * a3 + bf2f((unsigned short)(sv.y >> 16)) * dv2;
    uint2 ov = make_uint2(((unsigned)f2bf(r1) << 16) | f2bf(r0), ((unsigned)f2bf(r3) << 16) | f2bf(r2));
    *(uint2*)(out + (size_t)v * 256 + f0) = ov;
}

// ---------------- score matvec ----------------
__global__ __launch_bounds__(256) void score_mv_kernel(const unsigned short* __restrict__ hf,
                                                       const void* __restrict__ wp, const void* __restrict__ wn,
                                                       float* __restrict__ svp, float* __restrict__ svn) {
    int wave = threadIdx.x >> 6, lane = threadIdx.x & 63;
    int v = blockIdx.x * 4 + wave;
    float sp = 0.f, sn = 0.f;
#pragma unroll
    for (int i = 0; i < 3; i++) {
        int k = i * 256 + lane * 4;
        uint2 hv = *(const uint2*)(hf + (size_t)v * 768 + k);
        float x0 = bf2f((unsigned short)(hv.x & 0xffff));
        float x1 = bf2f((unsigned short)(hv.x >> 16));
        float x2 = bf2f((unsigned short)(hv.y & 0xffff));
        float x3 = bf2f((unsigned short)(hv.y >> 16));
        sp += x0 * in_ld(wp, k) + x1 * in_ld(wp, k + 1) + x2 * in_ld(wp, k + 2) + x3 * in_ld(wp, k + 3);
        sn += x0 * in_ld(wn, k) + x1 * in_ld(wn, k + 1) + x2 * in_ld(wn, k + 2) + x3 * in_ld(wn, k + 3);
    }
    for (int off = 32; off >= 1; off >>= 1) {
        sp += __shfl_down(sp, off, 64);
        sn += __shfl_down(sn, off, 64);
    }
    if (lane == 0) { svp[v] = sp; svn[v] = sn; }
}

// ---------------- fused: score aggregation + sigmoid + outputs + dual top-k ----------------
__global__ __launch_bounds__(512) void score_topk_kernel(const float* __restrict__ svp, const float* __restrict__ svn,
                                                         const int* __restrict__ rowptr, const int* __restrict__ srcs,
                                                         const float* __restrict__ dinv,
                                                         const void* __restrict__ bp, const void* __restrict__ bn_,
                                                         unsigned char* __restrict__ maskp,
                                                         unsigned char* __restrict__ maskn,
                                                         void* __restrict__ dout) {
    __shared__ float sp[512], sn[512];
    int g = blockIdx.x, i = threadIdx.x;
    int v = g * 512 + i;
    float ap = 0.f, an = 0.f;
    int s = rowptr[v], e = rowptr[v + 1];
    for (int k = s; k < e; k++) {
        int u = srcs[k] & (N_NODES - 1);
        float du = dinv[u];
        ap += svp[u] * du;
        an += svn[u] * du;
    }
    float dv = dinv[v], dv2 = dv * dv;
    float zp = dv * ap + svp[v] * dv2 + in_ld(bp, 0);
    float zn = dv * an + svn[v] * dv2 + in_ld(bn_, 0);
    float pp = 1.0f / (1.0f + __expf(-zp));
    float pn = 1.0f / (1.0f + __expf(-zn));
    st_out(dout, 1920 + (size_t)v, pp);
    st_out(dout, 1920 + (size_t)N_NODES + v, pn);
    st_out(dout, 1920 + 2 * (size_t)N_NODES + v, (float)g);
    sp[i] = pp; sn[i] = pn;
    __syncthreads();
    int cp = 0, cn = 0;
    for (int j = 0; j < 512; j++) {
        float op = sp[j], on = sn[j];
        cp += (int)((op > pp) || ((op == pp) && (j < i)));
        cn += (int)((on > pn) || ((on == pn) && (j < i)));
    }
    maskp[v] = (cp < TOPK) ? 1 : 0;
    maskn[v] = (cn < TOPK) ? 1 : 0;
}

// ---------------- fused dual-mask readout ----------------
__global__ __launch_bounds__(256) void readout2_kernel(const unsigned short* __restrict__ xt,
                                                       const unsigned char* __restrict__ maskp,
                                                       const unsigned char* __restrict__ maskn,
                                                       float* __restrict__ eout) {
    int g = blockIdx.x;
    int c = blockIdx.y;
    int wv = threadIdx.x >> 6, lane = threadIdx.x & 63;
    int f = c * 64 + lane;
    __shared__ unsigned char mp[512], mn[512];
    __shared__ float red[4][64][4];
    for (int i = threadIdx.x; i < 512; i += 256) {
        mp[i] = maskp[(size_t)g * 512 + i];
        mn[i] = maskn[(size_t)g * 512 + i];
    }
    __syncthreads();
    float sp = 0.f, sn = 0.f, xp = -INFINITY, xn = -INFINITY;
    const unsigned short* base = xt + ((size_t)g * 512 + wv * 128) * 768 + f;
    for (int v = 0; v < 128; v++) {
        unsigned char bp = mp[wv * 128 + v], bn_ = mn[wv * 128 + v];
        if (!(bp | bn_)) continue;
        float x = bf2f(base[(size_t)v * 768]);
        if (bp) { sp += x; xp = fmaxf(xp, x); }
        if (bn_) { sn += x; xn = fmaxf(xn, x); }
    }
    red[wv][lane][0] = sp; red[wv][lane][1] = xp;
    red[wv][lane][2] = sn; red[wv][lane][3] = xn;
    __syncthreads();
    if (wv == 0) {
#pragma unroll
        for (int w = 1; w < 4; w++) {
            sp += red[w][lane][0]; xp = fmaxf(xp, red[w][lane][1]);
            sn += red[w][lane][2]; xn = fmaxf(xn, red[w][lane][3]);
        }
        float* erp = eout + (size_t)g * 1536;
        float* ern = eout + (size_t)(64 + g) * 1536;
        erp[f] = sp * (1.0f / TOPK);
        erp[768 + f] = xp;
        ern[f] = sn * (1.0f / TOPK);
        ern[768 + f] = xn;
    }
}

// ---------------- MLP GEMM, k-split + n-split (r10 proven) ----------------
__global__ __launch_bounds__(256) void mlp_gemm2_kernel(const float* __restrict__ in,
                                                        const float* __restrict__ W,
                                                        const float* __restrict__ b,
                                                        float* __restrict__ out, int K) {
    __shared__ float row[1536];
    __shared__ float red[4][64];
    int r = blockIdx.x, cg = blockIdx.y;
    int wv = threadIdx.x >> 6, lane = threadIdx.x & 63;
    int c = cg * 64 + lane;
    for (int k = threadIdx.x; k < K; k += 256) row[k] = in[(size_t)r * K + k];
    __syncthreads();
    int kpw = K >> 2;
    const float* wp = W + (size_t)(wv * kpw) * 256 + c;
    const float* rp = row + wv * kpw;
    float acc = 0.f;
#pragma unroll 4
    for (int k = 0; k < kpw; k++)
        acc += rp[k] * wp[(size_t)k * 256];
    red[wv][lane] = acc;
    __syncthreads();
    if (wv == 0) {
        float v = red[0][lane] + red[1][lane] + red[2][lane] + red[3][lane] + b[c];
        out[(size_t)r * 256 + c] = v;
    }
}

__global__ __launch_bounds__(64) void bn_kernel(const float* __restrict__ z, const void* __restrict__ gamma,
                                                const void* __restrict__ beta, const float* __restrict__ res,
                                                float* __restrict__ out) {
    int f = blockIdx.x & 255, g = blockIdx.x >> 8, r = threadIdx.x;
    size_t idx = (size_t)(g * 64 + r) * 256 + f;
    float x = z[idx];
    float s = x, sq = x * x;
    for (int off = 1; off < 64; off <<= 1) {
        s += __shfl_xor(s, off, 64);
        sq += __shfl_xor(sq, off, 64);
    }
    float m = s * (1.0f / 64.0f);
    float var = sq * (1.0f / 64.0f) - m * m;
    float y = (x - m) * rsqrtf(var + BN_EPS) * in_ld(gamma, f) + in_ld(beta, f);
    y = fmaxf(y, 0.0f);
    if (res) y += res[idx];
    out[idx] = y;
}

// fused logits + softmax
__global__ __launch_bounds__(64) void head_kernel(const float* __restrict__ act, const void* __restrict__ w4,
                                                  const void* __restrict__ b4, void* __restrict__ dout) {
    __shared__ float l[NCLS];
    int r = blockIdx.x, t = threadIdx.x;
    if (t < NCLS) {
        float acc = in_ld(b4, t);
        for (int k = 0; k < 256; k++)
            acc += act[(size_t)r * 256 + k] * in_ld(w4, (size_t)k * NCLS + t);
        l[t] = acc;
    }
    __syncthreads();
    if (t == 0) {
        float mx = -1e30f;
        for (int c = 0; c < NCLS; c++) mx = fmaxf(mx, l[c]);
        float ex[NCLS], sum = 0.f;
        for (int c = 0; c < NCLS; c++) { ex[c] = __expf(l[c] - mx); sum += ex[c]; }
        float inv = 1.0f / sum;
        int g = r >> 6, rr = r & 63;
        if (g == 0) {
            for (int c = 0; c < NCLS; c++) st_out(dout, (size_t)rr * NCLS + c, l[c]);
            for (int c = 0; c < NCLS; c++) st_out(dout, 640 + (size_t)rr * NCLS + c, ex[c] * inv);
        } else {
            for (int c = 0; c < NCLS; c++) st_out(dout, 1280 + (size_t)rr * NCLS + c, ex[c] * inv);
        }
    }
}

// ---------------- host launcher ----------------
extern "C" void kernel_launch(void* const* d_in, const int* in_sizes, int n_in,
                              void* d_out, int out_size, void* d_ws, size_t ws_size,
                              hipStream_t stream) {
    (void)in_sizes; (void)n_in; (void)out_size; (void)ws_size;

    const float* x = (const float*)d_in[0];
    const int* eb = (const int*)d_in[1];
    const float* w_s1 = (const float*)d_in[3];
    const float* b_s1 = (const float*)d_in[4];
    const float* w_s21 = (const float*)d_in[5];
    const float* b_s21 = (const float*)d_in[6];
    const float* w_s22 = (const float*)d_in[7];
    const float* b_s22 = (const float*)d_in[8];
    const float* w_raw = (const float*)d_in[9];
    const float* b_raw = (const float*)d_in[10];
    const void* w_pos = d_in[11];
    const void* b_pos = d_in[12];
    const void* w_neg = d_in[13];
    const void* b_neg = d_in[14];
    const float* w_pool = (const float*)d_in[15];
    const float* b_pool = (const float*)d_in[16];
    const float* w1 = (const float*)d_in[17];  const float* b1 = (const float*)d_in[18];
    const void* g1 = d_in[19];  const void* be1 = d_in[20];
    const float* w2 = (const float*)d_in[21];  const float* b2 = (const float*)d_in[22];
    const void* g2 = d_in[23];  const void* be2 = d_in[24];
    const float* w3 = (const float*)d_in[25];  const float* b3 = (const float*)d_in[26];
    const void* g3 = d_in[27];  const void* be3 = d_in[28];
    const void* w4 = d_in[29];  const void* b4 = d_in[30];

    char* ws = (char*)d_ws;
    size_t off = 0;
    auto alloc = [&](size_t b) -> void* {
        void* p = ws + off;
        off += (b + 255) & ~(size_t)255;
        return p;
    };
    int* flag = (int*)alloc(256);
    int* deg = (int*)alloc((size_t)N_NODES * 4);           // contiguous after flag
    float* dinv = (float*)alloc((size_t)N_NODES * 4);
    int* rowptr = (int*)alloc((size_t)(N_NODES + 1) * 4);
    int* cursor = (int*)alloc((size_t)N_NODES * 4);
    int* srcs = (int*)alloc((size_t)NEDGE * 4);
    unsigned short* xbf = (unsigned short*)alloc((size_t)N_NODES * 256 * 2);
    unsigned short* wcat2 = (unsigned short*)alloc((size_t)512 * 256 * 2);
    unsigned short* wb_s22 = (unsigned short*)alloc((size_t)256 * 256 * 2);
    unsigned short* wb_raw = (unsigned short*)alloc((size_t)256 * 256 * 2);
    unsigned short* wb_pool = (unsigned short*)alloc((size_t)768 * 768 * 2);
    unsigned short* Xa = (unsigned short*)alloc((size_t)N_NODES * 256 * 2);
    unsigned short* t1 = (unsigned short*)alloc((size_t)N_NODES * 256 * 2);
    unsigned short* t1a = (unsigned short*)alloc((size_t)N_NODES * 256 * 2);
    unsigned short* hfin = (unsigned short*)alloc((size_t)N_NODES * 768 * 2);
    unsigned short* xt = (unsigned short*)alloc((size_t)N_NODES * 768 * 2);
    float* svp = (float*)alloc((size_t)N_NODES * 4);
    float* svn = (float*)alloc((size_t)N_NODES * 4);
    unsigned char* maskp = (unsigned char*)alloc(N_NODES);
    unsigned char* maskn = (unsigned char*)alloc(N_NODES);
    float* ebuf = (float*)alloc((size_t)128 * 1536 * 4);
    float* zb = (float*)alloc((size_t)128 * 256 * 4);
    float* act1 = (float*)alloc((size_t)128 * 256 * 4);
    float* act2 = (float*)alloc((size_t)128 * 256 * 4);
    float* act3 = (float*)alloc((size_t)128 * 256 * 4);

    hipMemsetAsync(flag, 0, 256 + (size_t)N_NODES * 4, stream);

    detect_kernel<<<NEDGE / 256, 256, 0, stream>>>(eb, flag);
    hist_kernel<<<NEDGE / 256, 256, 0, stream>>>(eb, flag, deg);
    scan_kernel<<<1, 1024, 0, stream>>>(deg, rowptr, cursor, dinv);
    scatter_kernel<<<NEDGE / 256, 256, 0, stream>>>(eb, flag, cursor, srcs);

    cvt_all_kernel<<<4928, 256, 0, stream>>>(x, w_s1, w_s21, w_s22, w_raw, w_pool,
                                             xbf, wcat2, wb_s22, wb_raw, wb_pool);

    dim3 gA6(6, N_NODES / 128);
    dim3 gA1(2, N_NODES / 128);
    dim3 gP(6, N_NODES / 128);

    // GCN pipeline (r10 proven configuration)
    lin_agg_kernel<<<N_NODES / 4, 256, 0, stream>>>(xbf, rowptr, srcs, dinv, Xa);
    gemmA6_kernel<<<gA6, 256, 0, stream>>>(Xa, wcat2, xbf, wb_raw, b_s1, b_s21, b_raw, hfin, t1);
    lin_agg_kernel<<<N_NODES / 4, 256, 0, stream>>>(t1, rowptr, srcs, dinv, t1a);
    gemm_kernel<<<gA1, 256, 0, stream>>>(t1a, wb_s22, b_s22, hfin, 256, 768, 256, 2);
    // pool (N=768 proven shape)
    gemm_kernel<<<gP, 256, 0, stream>>>(hfin, wb_pool, b_pool, xt, 768, 768, 0, 1);
    // scores + top-k (fused) + readout
    score_mv_kernel<<<N_NODES / 4, 256, 0, stream>>>(hfin, w_pos, w_neg, svp, svn);
    score_topk_kernel<<<NGRAPH, 512, 0, stream>>>(svp, svn, rowptr, srcs, dinv, b_pos, b_neg,
                                                  maskp, maskn, d_out);
    {
        dim3 gR(NGRAPH, FDIM / 64);
        readout2_kernel<<<gR, 256, 0, stream>>>(xt, maskp, maskn, ebuf);
    }
    // MLP (r10 proven configuration)
    {
        dim3 gM(128, 4);
        mlp_gemm2_kernel<<<gM, 256, 0, stream>>>(ebuf, w1, b1, zb, 1536);
        bn_kernel<<<512, 64, 0, stream>>>(zb, g1, be1, nullptr, act1);
        mlp_gemm2_kernel<<<gM, 256, 0, stream>>>(act1, w2, b2, zb, 256);
        bn_kernel<<<512, 64, 0, stream>>>(zb, g2, be2, act1, act2);
        mlp_gemm2_kernel<<<gM, 256, 0, stream>>>(act2, w3, b3, zb, 256);
        bn_kernel<<<512, 64, 0, stream>>>(zb, g3, be3, act2, act3);
    }
    head_kernel<<<128, 64, 0, stream>>>(act3, w4, b4, d_out);
}